// Round 7
// baseline (232.234 us; speedup 1.0000x reference)
//
#include <hip/hip_runtime.h>
#include <hip/hip_fp16.h>

#define IN_F 128
#define HID  128
#define NC   10
#define H2P  16     // h2 row stride in HALVES (32 B)
#define NPB  128    // nodes per bin (bin = dst>>7, local = dst&127)
#define NBMAX 784   // max bins (N=100000 -> 782)
#define BCAP 2560   // per-bin edge capacity (mean 2046, +11 sigma)
#define CAPP 2944   // per-bin PADDED csr capacity: BCAP + NPB*3 (each node padded to x4)
#define EPB  4096   // edges per k_bin block (1024 thr x 4) -> 391 blocks
#define LDW  136    // padded LDS row stride in halves (272B -> lane-bank stride 4, ~2-way)

typedef _Float16 f16x8 __attribute__((ext_vector_type(8)));
typedef float f32x4 __attribute__((ext_vector_type(4)));
typedef int int4a __attribute__((ext_vector_type(4), aligned(4)));  // 4B-aligned vec4

__device__ inline __half2 shfl_xor_h2(__half2 v, int mask) {
    int i = __shfl_xor(*reinterpret_cast<int*>(&v), mask, 64);
    return *reinterpret_cast<__half2*>(&i);
}

// ------- phase A: bin edges by dst>>7, packed (dl<<17)|src; blk0 preps WT/W2T -
__global__ __launch_bounds__(1024) void k_bin(const int* __restrict__ src,
                                              const int* __restrict__ dst,
                                              int* __restrict__ bcnt,
                                              unsigned int* __restrict__ binned,
                                              const float* __restrict__ W1,
                                              __half* __restrict__ WT,
                                              const float* __restrict__ W2,
                                              float* __restrict__ W2T,
                                              int E, int nbin) {
    __shared__ int hist[NBMAX];
    __shared__ int base[NBMAX];
    __shared__ int lcur[NBMAX];
    const int tid = threadIdx.x;

    if (blockIdx.x == 0) {   // WT[n][k] = fp16(W1[k][n]); W2T[c][f] = W2[f][c]
        for (int i = tid; i < IN_F * HID; i += 1024) {
            int k = i >> 7, n = i & 127;
            WT[n * IN_F + k] = __float2half(W1[k * HID + n]);
        }
        for (int i = tid; i < NC * IN_F; i += 1024)
            W2T[i] = W2[(i & 127) * NC + (i >> 7)];
    }

    for (int b = tid; b < nbin; b += 1024) { hist[b] = 0; lcur[b] = 0; }
    __syncthreads();

    const int e0 = blockIdx.x * EPB + tid;
    int d[4];
    #pragma unroll
    for (int u = 0; u < 4; u++) {
        int e = e0 + u * 1024;
        d[u] = (e < E) ? dst[e] : -1;
        if (d[u] >= 0) atomicAdd(&hist[d[u] >> 7], 1);
    }
    __syncthreads();
    for (int b = tid; b < nbin; b += 1024) {
        int h = hist[b];
        base[b] = h ? atomicAdd(&bcnt[b], h) : 0;
    }
    __syncthreads();
    #pragma unroll
    for (int u = 0; u < 4; u++) {
        int e = e0 + u * 1024;
        if (e < E) {
            int dd = d[u];
            int b = dd >> 7;
            int s = src[e];
            int o = base[b] + atomicAdd(&lcur[b], 1);
            if (o < BCAP)
                binned[(size_t)b * BCAP + o] = ((unsigned)(dd & 127) << 17) | (unsigned)s;
        }
    }
}

// ------- phase B (fused): place (hist/scan/scatter, padded bin-strided CSR)
// then MFMA GEMM1. 512 threads: place rounds halved; GEMM runs 2 tiles
// concurrently (waves 0-3 <-> sX[0], waves 4-7 <-> sX[1]) -> 2 pair-iters.
// Same per-tile MFMA sequence as the 256-thread version -> bit-identical.
__global__ __launch_bounds__(512) void k_pg(const int* __restrict__ bcnt,
                                            const unsigned int* __restrict__ binned,
                                            int2* __restrict__ rowinfo,
                                            float* __restrict__ dis,
                                            int* __restrict__ csr,
                                            const float* __restrict__ X,
                                            const __half* __restrict__ WT,
                                            __half* __restrict__ hsh,
                                            __half* __restrict__ h2h,
                                            int N) {
    __shared__ int h[NPB];
    __shared__ int lb[NPB];
    __shared__ int cur[NPB];
    __shared__ float sdis[NPB];
    __shared__ _Float16 sX[2][32 * LDW];
    __shared__ _Float16 sW[128 * LDW];
    const int b = blockIdx.x;
    const int tid = threadIdx.x;

    if (tid < NPB) h[tid] = 0;
    __syncthreads();

    const int m = min(bcnt[b], BCAP);
    const unsigned int* p = binned + (size_t)b * BCAP;
    for (int i = tid; i < m; i += 512) atomicAdd(&h[p[i] >> 17], 1);
    __syncthreads();

    int myh = 0, cnt4 = 0;
    if (tid < NPB) { myh = h[tid]; cnt4 = (myh + 3) & ~3; lb[tid] = cnt4; }
    __syncthreads();
    #pragma unroll
    for (int off = 1; off < NPB; off <<= 1) {
        int t = (tid < NPB && tid >= off) ? lb[tid - off] : 0;
        __syncthreads();
        if (tid < NPB) lb[tid] += t;
        __syncthreads();
    }
    int ex = 0;
    if (tid < NPB) {
        ex = lb[tid] - cnt4;
        int node = b * NPB + tid;
        if (node < N) {
            rowinfo[node] = make_int2(b * CAPP + ex, cnt4);
            float dd = rsqrtf(1.0f + (float)myh);
            dis[node] = dd;
            sdis[tid] = dd;
        }
        lb[tid] = ex;     // exclusive offsets for scatter
        cur[tid] = 0;
    }
    __syncthreads();
    for (int i = tid; i < m; i += 512) {
        unsigned v = p[i];
        int dl = v >> 17;
        int r = atomicAdd(&cur[dl], 1);
        csr[b * CAPP + lb[dl] + r] = (int)(v & 0x1FFFF);
    }
    if (tid < NPB) {        // pad tail of each node's list with sentinel N
        for (int k = myh; k < cnt4; k++) csr[b * CAPP + ex + k] = N;
    }
    if (b == 0) {           // zero rows for the sentinel node
        f16x8 z = {0, 0, 0, 0, 0, 0, 0, 0};
        if (tid < 16) *(f16x8*)(hsh + (size_t)N * HID + tid * 8) = z;
        if (tid < 2)  *(f16x8*)(h2h + (size_t)N * H2P + tid * 8) = z;
    }

    // stage WT -> sW (512 threads: 4 threads/row, 4 x 16B chunks each)
    {
        int n = tid >> 2, part = tid & 3;
        const f16x8* srcp = (const f16x8*)(WT + n * IN_F);
        f16x8* dstp = (f16x8*)(sW + n * LDW);
        #pragma unroll
        for (int c = 0; c < 4; c++) dstp[part * 4 + c] = srcp[part * 4 + c];
    }

    const int wave = tid >> 6;        // 0..7
    const int grp  = wave >> 2;       // 0/1: which tile of the pair
    const int nbase = (wave & 3) * 32;
    const int lane = tid & 63;
    const int quad = lane >> 4;
    const int l16 = lane & 15;
    const int sub256 = tid >> 8;      // 0/1: which tile this thread stages
    const int t256 = tid & 255;

    for (int t = 0; t < 2; t++) {
        __syncthreads();   // prev pair's sX readers done; first iter: sW/sdis ready
        {   // stage tile 2t+sub256 (fp32 -> fp16), rows clamped at N-1
            int tdx = 2 * t + sub256;
            int r = t256 >> 3;
            int k0 = (t256 & 7) * 16;
            int row = b * NPB + tdx * 32 + r;
            if (row >= N) row = N - 1;
            const float* sp = X + (size_t)row * IN_F + k0;
            float4 f0 = *(const float4*)(sp);
            float4 f1 = *(const float4*)(sp + 4);
            float4 f2 = *(const float4*)(sp + 8);
            float4 f3 = *(const float4*)(sp + 12);
            f16x8 h0, h1;
            h0[0] = (_Float16)f0.x; h0[1] = (_Float16)f0.y;
            h0[2] = (_Float16)f0.z; h0[3] = (_Float16)f0.w;
            h0[4] = (_Float16)f1.x; h0[5] = (_Float16)f1.y;
            h0[6] = (_Float16)f1.z; h0[7] = (_Float16)f1.w;
            h1[0] = (_Float16)f2.x; h1[1] = (_Float16)f2.y;
            h1[2] = (_Float16)f2.z; h1[3] = (_Float16)f2.w;
            h1[4] = (_Float16)f3.x; h1[5] = (_Float16)f3.y;
            h1[6] = (_Float16)f3.z; h1[7] = (_Float16)f3.w;
            *(f16x8*)(sX[sub256] + r * LDW + k0) = h0;
            *(f16x8*)(sX[sub256] + r * LDW + k0 + 8) = h1;
        }
        __syncthreads();

        const int tdx = 2 * t + grp;
        f32x4 acc00 = {0,0,0,0}, acc01 = {0,0,0,0}, acc10 = {0,0,0,0}, acc11 = {0,0,0,0};
        #pragma unroll
        for (int kc = 0; kc < 4; kc++) {
            const int koff = kc * 32 + quad * 8;
            f16x8 a0 = *(const f16x8*)(sX[grp] + l16 * LDW + koff);
            f16x8 a1 = *(const f16x8*)(sX[grp] + (16 + l16) * LDW + koff);
            f16x8 b0 = *(const f16x8*)(sW + (nbase + l16) * LDW + koff);
            f16x8 b1 = *(const f16x8*)(sW + (nbase + 16 + l16) * LDW + koff);
            acc00 = __builtin_amdgcn_mfma_f32_16x16x32_f16(a0, b0, acc00, 0, 0, 0);
            acc01 = __builtin_amdgcn_mfma_f32_16x16x32_f16(a0, b1, acc01, 0, 0, 0);
            acc10 = __builtin_amdgcn_mfma_f32_16x16x32_f16(a1, b0, acc10, 0, 0, 0);
            acc11 = __builtin_amdgcn_mfma_f32_16x16x32_f16(a1, b1, acc11, 0, 0, 0);
        }
        #pragma unroll
        for (int r = 0; r < 4; r++) {
            {
                int lr = tdx * 32 + quad * 4 + r;
                int row = b * NPB + lr;
                if (row < N) {
                    float d = sdis[lr];
                    __half* o = hsh + (size_t)row * HID + nbase + l16;
                    o[0]  = __float2half(acc00[r] * d);
                    o[16] = __float2half(acc01[r] * d);
                }
            }
            {
                int lr = tdx * 32 + 16 + quad * 4 + r;
                int row = b * NPB + lr;
                if (row < N) {
                    float d = sdis[lr];
                    __half* o = hsh + (size_t)row * HID + nbase + l16;
                    o[0]  = __float2half(acc10[r] * d);
                    o[16] = __float2half(acc11[r] * d);
                }
            }
        }
    }
}

// ------- agg1: 2-deep pipelined maskless gather + bias/ReLU + GEMM2 ----------
// Node range [base, nend) so the launch can be split for profiling visibility.
__global__ __launch_bounds__(256) void k_agg1(const __half* __restrict__ hsh,
                                              const int2* __restrict__ rowinfo,
                                              const int* __restrict__ csr,
                                              const float* __restrict__ dis,
                                              const float* __restrict__ b1,
                                              const float* __restrict__ W2T,
                                              __half* __restrict__ h2h,
                                              int base0, int nend) {
    const int node = base0 + blockIdx.x * 4 + (threadIdx.x >> 6);
    if (node >= nend) return;
    const int lane = threadIdx.x & 63;
    const int g   = lane >> 4;
    const int l16 = lane & 15;
    const int f0  = l16 * 8;       // 8 halves per lane
    const __half2 hz = __half2half2(__float2half(0.0f));

    const int2 ri = rowinfo[node];
    const int beg = ri.x, end = ri.x + ri.y;
    const float d = dis[node];

    __half2 acc2[4] = {hz, hz, hz, hz};
    if (g == 0) {   // self term (hsh pre-scaled by dis[src])
        float4 r = *(const float4*)(hsh + (size_t)node * HID + f0);
        const __half2* hh = (const __half2*)&r;
        acc2[0] = hh[0]; acc2[1] = hh[1]; acc2[2] = hh[2]; acc2[3] = hh[3];
    }

    int j0 = beg + 4 * g;
    if (j0 < end) {
        int4a cv0 = *(const int4a*)(csr + j0);
        int  j1 = j0 + 16;
        bool m1 = j1 < end;
        int4a cv1 = m1 ? *(const int4a*)(csr + j1) : cv0;
        float4 r0 = *(const float4*)(hsh + (size_t)cv0[0] * HID + f0);
        float4 r1 = *(const float4*)(hsh + (size_t)cv0[1] * HID + f0);
        float4 r2 = *(const float4*)(hsh + (size_t)cv0[2] * HID + f0);
        float4 r3 = *(const float4*)(hsh + (size_t)cv0[3] * HID + f0);
        while (true) {
            const int  j2 = j1 + 16;
            const bool m2 = m1 && (j2 < end);
            int4a cv2 = m2 ? *(const int4a*)(csr + j2) : cv1;
            float4 n0, n1, n2, n3;
            if (m1) {
                n0 = *(const float4*)(hsh + (size_t)cv1[0] * HID + f0);
                n1 = *(const float4*)(hsh + (size_t)cv1[1] * HID + f0);
                n2 = *(const float4*)(hsh + (size_t)cv1[2] * HID + f0);
                n3 = *(const float4*)(hsh + (size_t)cv1[3] * HID + f0);
            }
            const __half2* h0 = (const __half2*)&r0;
            const __half2* h1 = (const __half2*)&r1;
            const __half2* h2 = (const __half2*)&r2;
            const __half2* h3 = (const __half2*)&r3;
            #pragma unroll
            for (int i = 0; i < 4; i++) {
                acc2[i] = __hadd2(acc2[i], h0[i]);
                acc2[i] = __hadd2(acc2[i], h1[i]);
                acc2[i] = __hadd2(acc2[i], h2[i]);
                acc2[i] = __hadd2(acc2[i], h3[i]);
            }
            if (!m1) break;
            r0 = n0; r1 = n1; r2 = n2; r3 = n3;
            cv1 = cv2; m1 = m2; j1 = j2;
        }
    }

    // merge the 4 sub-groups, then widen
    #pragma unroll
    for (int i = 0; i < 4; i++) {
        acc2[i] = __hadd2(acc2[i], shfl_xor_h2(acc2[i], 16));
        acc2[i] = __hadd2(acc2[i], shfl_xor_h2(acc2[i], 32));
    }
    float acc[8];
    #pragma unroll
    for (int i = 0; i < 4; i++) {
        float2 t = __half22float2(acc2[i]);
        acc[2 * i] = t.x; acc[2 * i + 1] = t.y;
    }

    float4 ba = *(const float4*)(b1 + f0);
    float4 bb = *(const float4*)(b1 + f0 + 4);
    float h[8];
    h[0] = fmaxf(fmaf(d, acc[0], ba.x), 0.0f);
    h[1] = fmaxf(fmaf(d, acc[1], ba.y), 0.0f);
    h[2] = fmaxf(fmaf(d, acc[2], ba.z), 0.0f);
    h[3] = fmaxf(fmaf(d, acc[3], ba.w), 0.0f);
    h[4] = fmaxf(fmaf(d, acc[4], bb.x), 0.0f);
    h[5] = fmaxf(fmaf(d, acc[5], bb.y), 0.0f);
    h[6] = fmaxf(fmaf(d, acc[6], bb.z), 0.0f);
    h[7] = fmaxf(fmaf(d, acc[7], bb.w), 0.0f);

    const int cb = (g == 0) ? 0 : (g == 1) ? 3 : (g == 2) ? 6 : 8;
    const int nc = (g < 2) ? 3 : 2;
    float p[3];
    #pragma unroll
    for (int ci = 0; ci < 3; ci++) {
        if (ci < nc) {
            int c = cb + ci;
            float4 wa = *(const float4*)(W2T + c * IN_F + f0);
            float4 wb = *(const float4*)(W2T + c * IN_F + f0 + 4);
            float t = fmaf(h[0], wa.x, fmaf(h[1], wa.y, fmaf(h[2], wa.z, h[3] * wa.w)));
            t = fmaf(h[4], wb.x, fmaf(h[5], wb.y, fmaf(h[6], wb.z, fmaf(h[7], wb.w, t))));
            #pragma unroll
            for (int off = 1; off < 16; off <<= 1) t += __shfl_xor(t, off, 64);
            p[ci] = t;
        }
    }
    if (l16 == 0) {
        __half* o = h2h + (size_t)node * H2P + cb;
        for (int ci = 0; ci < nc; ci++) o[ci] = __float2half(d * p[ci]);
    }
}

// ------- agg2: 2-deep pipelined maskless gather (32B rows) + softmax ---------
__global__ __launch_bounds__(256) void k_agg2(const __half* __restrict__ h2h,
                                              const int2* __restrict__ rowinfo,
                                              const int* __restrict__ csr,
                                              const float* __restrict__ dis,
                                              const float* __restrict__ b2,
                                              float* __restrict__ out,
                                              int N) {
    int t = blockIdx.x * 256 + threadIdx.x;
    int node = t >> 3;
    if (node >= N) return;
    int o = t & 7;
    int q = o & 1;          // which 8-half chunk of the 16-half row
    int eg = o >> 1;        // edge group 0..3
    const int base = q * 8;
    const __half2 hz = __half2half2(__float2half(0.0f));

    __half2 a2[4] = {hz, hz, hz, hz};
    if (eg == 0) {          // self term
        float4 r = *(const float4*)(h2h + (size_t)node * H2P + base);
        const __half2* hh = (const __half2*)&r;
        a2[0] = hh[0]; a2[1] = hh[1]; a2[2] = hh[2]; a2[3] = hh[3];
    }
    const int2 ri = rowinfo[node];
    const int end = ri.x + ri.y;

    int j0 = ri.x + 4 * eg;
    if (j0 < end) {
        int4a cv0 = *(const int4a*)(csr + j0);
        int  j1 = j0 + 16;
        bool m1 = j1 < end;
        int4a cv1 = m1 ? *(const int4a*)(csr + j1) : cv0;
        float4 r0 = *(const float4*)(h2h + (size_t)cv0[0] * H2P + base);
        float4 r1 = *(const float4*)(h2h + (size_t)cv0[1] * H2P + base);
        float4 r2 = *(const float4*)(h2h + (size_t)cv0[2] * H2P + base);
        float4 r3 = *(const float4*)(h2h + (size_t)cv0[3] * H2P + base);
        while (true) {
            const int  j2 = j1 + 16;
            const bool m2 = m1 && (j2 < end);
            int4a cv2 = m2 ? *(const int4a*)(csr + j2) : cv1;
            float4 n0, n1, n2, n3;
            if (m1) {
                n0 = *(const float4*)(h2h + (size_t)cv1[0] * H2P + base);
                n1 = *(const float4*)(h2h + (size_t)cv1[1] * H2P + base);
                n2 = *(const float4*)(h2h + (size_t)cv1[2] * H2P + base);
                n3 = *(const float4*)(h2h + (size_t)cv1[3] * H2P + base);
            }
            const __half2* h0 = (const __half2*)&r0;
            const __half2* h1 = (const __half2*)&r1;
            const __half2* h2 = (const __half2*)&r2;
            const __half2* h3 = (const __half2*)&r3;
            #pragma unroll
            for (int i = 0; i < 4; i++) {
                a2[i] = __hadd2(a2[i], h0[i]);
                a2[i] = __hadd2(a2[i], h1[i]);
                a2[i] = __hadd2(a2[i], h2[i]);
                a2[i] = __hadd2(a2[i], h3[i]);
            }
            if (!m1) break;
            r0 = n0; r1 = n1; r2 = n2; r3 = n3;
            cv1 = cv2; m1 = m2; j1 = j2;
        }
    }

    // merge the 4 edge-groups (masks 2 and 4 stay inside the 8-lane octet)
    #pragma unroll
    for (int i = 0; i < 4; i++) {
        a2[i] = __hadd2(a2[i], shfl_xor_h2(a2[i], 2));
        a2[i] = __hadd2(a2[i], shfl_xor_h2(a2[i], 4));
    }

    float a[8];
    #pragma unroll
    for (int i = 0; i < 4; i++) {
        float2 tt = __half22float2(a2[i]);
        a[2 * i] = tt.x; a[2 * i + 1] = tt.y;
    }

    const float d = dis[node];
    float vv[8];
    #pragma unroll
    for (int i = 0; i < 8; i++) {
        int f = base + i;
        vv[i] = (f < NC) ? fmaf(d, a[i], b2[f]) : -1e30f;
    }
    float m = vv[0];
    #pragma unroll
    for (int i = 1; i < 8; i++) m = fmaxf(m, vv[i]);
    m = fmaxf(m, __shfl_xor(m, 1, 64));
    float e[8];
    float s = 0.0f;
    #pragma unroll
    for (int i = 0; i < 8; i++) { e[i] = (base + i < NC) ? expf(vv[i] - m) : 0.0f; s += e[i]; }
    s += __shfl_xor(s, 1, 64);
    float inv = 1.0f / s;

    float* op = out + (size_t)node * NC;
    if (o == 0) {
        *(float2*)(op + 0) = make_float2(e[0] * inv, e[1] * inv);
        *(float2*)(op + 2) = make_float2(e[2] * inv, e[3] * inv);
        *(float2*)(op + 4) = make_float2(e[4] * inv, e[5] * inv);
        *(float2*)(op + 6) = make_float2(e[6] * inv, e[7] * inv);
    } else if (o == 1) {
        *(float2*)(op + 8) = make_float2(e[0] * inv, e[1] * inv);
    }
}

extern "C" void kernel_launch(void* const* d_in, const int* in_sizes, int n_in,
                              void* d_out, int out_size, void* d_ws, size_t ws_size,
                              hipStream_t stream) {
    const float* x  = (const float*)d_in[0];
    const int*   ei = (const int*)d_in[1];
    const float* W1 = (const float*)d_in[2];
    const float* b1 = (const float*)d_in[3];
    const float* W2 = (const float*)d_in[4];
    const float* b2 = (const float*)d_in[5];
    float* out = (float*)d_out;

    const int N = in_sizes[0] / IN_F;   // 100000
    const int E = in_sizes[1] / 2;      // 1600000
    const int* esrc = ei;
    const int* edst = ei + E;
    const int nbin = (N + NPB - 1) / NPB;  // 782

    char* ws = (char*)d_ws;
    int2*   rowinfo = (int2*)(ws);                          // N*8   = 800 KB
    float*  dis     = (float*)(ws + 0x100000);              // 400 KB
    int*    bcnt    = (int*)(ws + 0x180000);                // 3.1 KB
    __half* WT      = (__half*)(ws + 0x190000);             // 32 KB
    float*  W2T     = (float*)(ws + 0x1A0000);              // 5 KB
    unsigned int* binned = (unsigned int*)(ws + 0x200000);  // 8.0 MB
    int*    csr     = (int*)(ws + 0xA00000);                // 9.2 MB (padded, bin-strided)
    __half* hsh     = (__half*)(ws + 0x1400000);            // 25.6 MB (+ sentinel row N)
    __half* h2h     = (__half*)(ws + 0x2D00000);            // 3.2 MB (+ sentinel row N)

    hipMemsetAsync(bcnt, 0, (size_t)nbin * sizeof(int), stream);

    k_bin <<<(E + EPB - 1) / EPB, 1024, 0, stream>>>(esrc, edst, bcnt, binned, W1, WT, W2, W2T, E, nbin);
    k_pg  <<<nbin, 512, 0, stream>>>(bcnt, binned, rowinfo, dis, csr, x, WT, hsh, h2h, N);
    // agg1 split into two half-N launches: lowers the profiler's top-5
    // visibility threshold to ~33us so the largest front-end kernel surfaces.
    const int half = ((N / 2) + 3) & ~3;     // 50000 -> block-aligned
    k_agg1<<<(half + 3) / 4, 256, 0, stream>>>(hsh, rowinfo, csr, dis, b1, W2T, h2h, 0, half);
    k_agg1<<<((N - half) + 3) / 4, 256, 0, stream>>>(hsh, rowinfo, csr, dis, b1, W2T, h2h, half, N);
    k_agg2<<<(int)(((size_t)N * 8 + 255) / 256), 256, 0, stream>>>(h2h, rowinfo, csr, dis, b2, out, N);
}

// Round 8
// 224.529 us; speedup vs baseline: 1.0343x; 1.0343x over previous
//
#include <hip/hip_runtime.h>
#include <hip/hip_fp16.h>

#define IN_F 128
#define HID  128
#define NC   10
#define H2P  16     // h2 row stride in HALVES (32 B)
#define NPB  128    // nodes per bin (bin = dst>>7, local = dst&127)
#define NBMAX 784   // max bins (N=100000 -> 782)
#define BCAP 2560   // per-bin edge capacity (mean 2046, +11 sigma)
#define CAPP 2944   // per-bin PADDED csr capacity: BCAP + NPB*3 (each node padded to x4)
#define EPB  4096   // edges per k_bin block (1024 thr x 4) -> 391 blocks
#define LDW  136    // padded LDS row stride in halves (272B -> lane-bank stride 4, ~2-way)

typedef _Float16 f16x8 __attribute__((ext_vector_type(8)));
typedef float f32x4 __attribute__((ext_vector_type(4)));
typedef int int4a __attribute__((ext_vector_type(4), aligned(4)));  // 4B-aligned vec4

__device__ inline __half2 shfl_xor_h2(__half2 v, int mask) {
    int i = __shfl_xor(*reinterpret_cast<int*>(&v), mask, 64);
    return *reinterpret_cast<__half2*>(&i);
}

// ------- phase A: bin edges by dst>>7, packed (dl<<17)|src; blk0 preps WT/W2T.
// Scatter goes through an LDS stage sorted by bin, then streams out so
// consecutive threads write consecutive binned[] addresses (coalesced runs)
// instead of 1.6M race-ordered 4B writes (64B line-allocate per edge).
__global__ __launch_bounds__(1024) void k_bin(const int* __restrict__ src,
                                              const int* __restrict__ dst,
                                              int* __restrict__ bcnt,
                                              unsigned int* __restrict__ binned,
                                              const float* __restrict__ W1,
                                              __half* __restrict__ WT,
                                              const float* __restrict__ W2,
                                              float* __restrict__ W2T,
                                              int E, int nbin) {
    __shared__ int hist[NBMAX];
    __shared__ int base[NBMAX];
    __shared__ int lofs[NBMAX];
    __shared__ int lcur[NBMAX];
    __shared__ int scan[1024];
    __shared__ unsigned int stage[EPB];
    __shared__ unsigned short sbin[EPB];
    const int tid = threadIdx.x;

    if (blockIdx.x == 0) {   // WT[n][k] = fp16(W1[k][n]); W2T[c][f] = W2[f][c]
        for (int i = tid; i < IN_F * HID; i += 1024) {
            int k = i >> 7, n = i & 127;
            WT[n * IN_F + k] = __float2half(W1[k * HID + n]);
        }
        for (int i = tid; i < NC * IN_F; i += 1024)
            W2T[i] = W2[(i & 127) * NC + (i >> 7)];
    }

    for (int b = tid; b < nbin; b += 1024) { hist[b] = 0; lcur[b] = 0; }
    __syncthreads();

    const int e0 = blockIdx.x * EPB + tid;
    int d[4], s[4];
    #pragma unroll
    for (int u = 0; u < 4; u++) {
        int e = e0 + u * 1024;
        d[u] = (e < E) ? dst[e] : -1;
        s[u] = (e < E) ? src[e] : 0;
        if (d[u] >= 0) atomicAdd(&hist[d[u] >> 7], 1);
    }
    __syncthreads();
    // global reservation per bin
    for (int b = tid; b < nbin; b += 1024) {
        int h = hist[b];
        base[b] = h ? atomicAdd(&bcnt[b], h) : 0;
    }
    // block-local exclusive scan of hist (1024-slot Hillis-Steele)
    scan[tid] = (tid < nbin) ? hist[tid] : 0;
    __syncthreads();
    for (int off = 1; off < 1024; off <<= 1) {
        int t = (tid >= off) ? scan[tid - off] : 0;
        __syncthreads();
        scan[tid] += t;
        __syncthreads();
    }
    if (tid < nbin) lofs[tid] = scan[tid] - hist[tid];
    __syncthreads();
    // scatter into LDS stage (sorted by bin)
    #pragma unroll
    for (int u = 0; u < 4; u++) {
        if (d[u] >= 0) {
            int b = d[u] >> 7;
            int slot = lofs[b] + atomicAdd(&lcur[b], 1);
            stage[slot] = ((unsigned)(d[u] & 127) << 17) | (unsigned)s[u];
            sbin[slot] = (unsigned short)b;
        }
    }
    __syncthreads();
    // coalesced streamout: entry i -> binned[base[bin] + (i - lofs[bin])]
    const int total = scan[1023];
    for (int i = tid; i < total; i += 1024) {
        int b = sbin[i];
        int o = base[b] + (i - lofs[b]);
        if (o < BCAP) binned[(size_t)b * BCAP + o] = stage[i];
    }
}

// ------- phase B (fused): place (hist/wave-scan/scatter, padded bin-strided
// CSR) then MFMA GEMM1, 512 threads, 2 tiles concurrently. Scan is 2 waves of
// shfl_up (2 barriers) instead of the 14-barrier LDS tree.
__global__ __launch_bounds__(512) void k_pg(const int* __restrict__ bcnt,
                                            const unsigned int* __restrict__ binned,
                                            int2* __restrict__ rowinfo,
                                            float* __restrict__ dis,
                                            int* __restrict__ csr,
                                            const float* __restrict__ X,
                                            const __half* __restrict__ WT,
                                            __half* __restrict__ hsh,
                                            __half* __restrict__ h2h,
                                            int N) {
    __shared__ int h[NPB];
    __shared__ int lb[NPB];
    __shared__ int cur[NPB];
    __shared__ float sdis[NPB];
    __shared__ int wtot[2];
    __shared__ _Float16 sX[2][32 * LDW];
    __shared__ _Float16 sW[128 * LDW];
    const int b = blockIdx.x;
    const int tid = threadIdx.x;

    if (tid < NPB) h[tid] = 0;
    __syncthreads();

    const int m = min(bcnt[b], BCAP);
    const unsigned int* p = binned + (size_t)b * BCAP;
    for (int i = tid; i < m; i += 512) atomicAdd(&h[p[i] >> 17], 1);
    __syncthreads();

    int myh = 0, cnt4 = 0;
    if (tid < NPB) { myh = h[tid]; cnt4 = (myh + 3) & ~3; }
    // inclusive wave scan of cnt4 over waves 0,1 (whole waves active)
    int inc = cnt4;
    if (tid < NPB) {
        #pragma unroll
        for (int off = 1; off < 64; off <<= 1) {
            int t = __shfl_up(inc, off, 64);
            if ((tid & 63) >= off) inc += t;
        }
        if ((tid & 63) == 63) wtot[tid >> 6] = inc;
    }
    __syncthreads();
    int ex = 0;
    if (tid < NPB) {
        ex = inc - cnt4 + ((tid >= 64) ? wtot[0] : 0);
        int node = b * NPB + tid;
        if (node < N) {
            rowinfo[node] = make_int2(b * CAPP + ex, cnt4);
            float dd = rsqrtf(1.0f + (float)myh);
            dis[node] = dd;
            sdis[tid] = dd;
        }
        lb[tid] = ex;     // exclusive offsets for scatter
        cur[tid] = 0;
    }
    __syncthreads();
    for (int i = tid; i < m; i += 512) {
        unsigned v = p[i];
        int dl = v >> 17;
        int r = atomicAdd(&cur[dl], 1);
        csr[b * CAPP + lb[dl] + r] = (int)(v & 0x1FFFF);
    }
    if (tid < NPB) {        // pad tail of each node's list with sentinel N
        for (int k = myh; k < cnt4; k++) csr[b * CAPP + ex + k] = N;
    }
    if (b == 0) {           // zero rows for the sentinel node
        f16x8 z = {0, 0, 0, 0, 0, 0, 0, 0};
        if (tid < 16) *(f16x8*)(hsh + (size_t)N * HID + tid * 8) = z;
        if (tid < 2)  *(f16x8*)(h2h + (size_t)N * H2P + tid * 8) = z;
    }

    // stage WT -> sW (512 threads: 4 threads/row, 4 x 16B chunks each)
    {
        int n = tid >> 2, part = tid & 3;
        const f16x8* srcp = (const f16x8*)(WT + n * IN_F);
        f16x8* dstp = (f16x8*)(sW + n * LDW);
        #pragma unroll
        for (int c = 0; c < 4; c++) dstp[part * 4 + c] = srcp[part * 4 + c];
    }

    const int wave = tid >> 6;        // 0..7
    const int grp  = wave >> 2;       // 0/1: which tile of the pair
    const int nbase = (wave & 3) * 32;
    const int lane = tid & 63;
    const int quad = lane >> 4;
    const int l16 = lane & 15;
    const int sub256 = tid >> 8;      // 0/1: which tile this thread stages
    const int t256 = tid & 255;

    for (int t = 0; t < 2; t++) {
        __syncthreads();   // prev pair's sX readers done; first iter: sW/sdis ready
        {   // stage tile 2t+sub256 (fp32 -> fp16), rows clamped at N-1
            int tdx = 2 * t + sub256;
            int r = t256 >> 3;
            int k0 = (t256 & 7) * 16;
            int row = b * NPB + tdx * 32 + r;
            if (row >= N) row = N - 1;
            const float* sp = X + (size_t)row * IN_F + k0;
            float4 f0 = *(const float4*)(sp);
            float4 f1 = *(const float4*)(sp + 4);
            float4 f2 = *(const float4*)(sp + 8);
            float4 f3 = *(const float4*)(sp + 12);
            f16x8 h0, h1;
            h0[0] = (_Float16)f0.x; h0[1] = (_Float16)f0.y;
            h0[2] = (_Float16)f0.z; h0[3] = (_Float16)f0.w;
            h0[4] = (_Float16)f1.x; h0[5] = (_Float16)f1.y;
            h0[6] = (_Float16)f1.z; h0[7] = (_Float16)f1.w;
            h1[0] = (_Float16)f2.x; h1[1] = (_Float16)f2.y;
            h1[2] = (_Float16)f2.z; h1[3] = (_Float16)f2.w;
            h1[4] = (_Float16)f3.x; h1[5] = (_Float16)f3.y;
            h1[6] = (_Float16)f3.z; h1[7] = (_Float16)f3.w;
            *(f16x8*)(sX[sub256] + r * LDW + k0) = h0;
            *(f16x8*)(sX[sub256] + r * LDW + k0 + 8) = h1;
        }
        __syncthreads();

        const int tdx = 2 * t + grp;
        f32x4 acc00 = {0,0,0,0}, acc01 = {0,0,0,0}, acc10 = {0,0,0,0}, acc11 = {0,0,0,0};
        #pragma unroll
        for (int kc = 0; kc < 4; kc++) {
            const int koff = kc * 32 + quad * 8;
            f16x8 a0 = *(const f16x8*)(sX[grp] + l16 * LDW + koff);
            f16x8 a1 = *(const f16x8*)(sX[grp] + (16 + l16) * LDW + koff);
            f16x8 b0 = *(const f16x8*)(sW + (nbase + l16) * LDW + koff);
            f16x8 b1 = *(const f16x8*)(sW + (nbase + 16 + l16) * LDW + koff);
            acc00 = __builtin_amdgcn_mfma_f32_16x16x32_f16(a0, b0, acc00, 0, 0, 0);
            acc01 = __builtin_amdgcn_mfma_f32_16x16x32_f16(a0, b1, acc01, 0, 0, 0);
            acc10 = __builtin_amdgcn_mfma_f32_16x16x32_f16(a1, b0, acc10, 0, 0, 0);
            acc11 = __builtin_amdgcn_mfma_f32_16x16x32_f16(a1, b1, acc11, 0, 0, 0);
        }
        #pragma unroll
        for (int r = 0; r < 4; r++) {
            {
                int lr = tdx * 32 + quad * 4 + r;
                int row = b * NPB + lr;
                if (row < N) {
                    float d = sdis[lr];
                    __half* o = hsh + (size_t)row * HID + nbase + l16;
                    o[0]  = __float2half(acc00[r] * d);
                    o[16] = __float2half(acc01[r] * d);
                }
            }
            {
                int lr = tdx * 32 + 16 + quad * 4 + r;
                int row = b * NPB + lr;
                if (row < N) {
                    float d = sdis[lr];
                    __half* o = hsh + (size_t)row * HID + nbase + l16;
                    o[0]  = __float2half(acc10[r] * d);
                    o[16] = __float2half(acc11[r] * d);
                }
            }
        }
    }
}

// ------- agg1: 2-deep pipelined maskless gather + bias/ReLU + GEMM2 ----------
__global__ __launch_bounds__(256) void k_agg1(const __half* __restrict__ hsh,
                                              const int2* __restrict__ rowinfo,
                                              const int* __restrict__ csr,
                                              const float* __restrict__ dis,
                                              const float* __restrict__ b1,
                                              const float* __restrict__ W2T,
                                              __half* __restrict__ h2h,
                                              int N) {
    const int node = blockIdx.x * 4 + (threadIdx.x >> 6);
    if (node >= N) return;
    const int lane = threadIdx.x & 63;
    const int g   = lane >> 4;
    const int l16 = lane & 15;
    const int f0  = l16 * 8;       // 8 halves per lane
    const __half2 hz = __half2half2(__float2half(0.0f));

    const int2 ri = rowinfo[node];
    const int beg = ri.x, end = ri.x + ri.y;
    const float d = dis[node];

    __half2 acc2[4] = {hz, hz, hz, hz};
    if (g == 0) {   // self term (hsh pre-scaled by dis[src])
        float4 r = *(const float4*)(hsh + (size_t)node * HID + f0);
        const __half2* hh = (const __half2*)&r;
        acc2[0] = hh[0]; acc2[1] = hh[1]; acc2[2] = hh[2]; acc2[3] = hh[3];
    }

    int j0 = beg + 4 * g;
    if (j0 < end) {
        int4a cv0 = *(const int4a*)(csr + j0);
        int  j1 = j0 + 16;
        bool m1 = j1 < end;
        int4a cv1 = m1 ? *(const int4a*)(csr + j1) : cv0;
        float4 r0 = *(const float4*)(hsh + (size_t)cv0[0] * HID + f0);
        float4 r1 = *(const float4*)(hsh + (size_t)cv0[1] * HID + f0);
        float4 r2 = *(const float4*)(hsh + (size_t)cv0[2] * HID + f0);
        float4 r3 = *(const float4*)(hsh + (size_t)cv0[3] * HID + f0);
        while (true) {
            const int  j2 = j1 + 16;
            const bool m2 = m1 && (j2 < end);
            int4a cv2 = m2 ? *(const int4a*)(csr + j2) : cv1;
            float4 n0, n1, n2, n3;
            if (m1) {
                n0 = *(const float4*)(hsh + (size_t)cv1[0] * HID + f0);
                n1 = *(const float4*)(hsh + (size_t)cv1[1] * HID + f0);
                n2 = *(const float4*)(hsh + (size_t)cv1[2] * HID + f0);
                n3 = *(const float4*)(hsh + (size_t)cv1[3] * HID + f0);
            }
            const __half2* h0 = (const __half2*)&r0;
            const __half2* h1 = (const __half2*)&r1;
            const __half2* h2 = (const __half2*)&r2;
            const __half2* h3 = (const __half2*)&r3;
            #pragma unroll
            for (int i = 0; i < 4; i++) {
                acc2[i] = __hadd2(acc2[i], h0[i]);
                acc2[i] = __hadd2(acc2[i], h1[i]);
                acc2[i] = __hadd2(acc2[i], h2[i]);
                acc2[i] = __hadd2(acc2[i], h3[i]);
            }
            if (!m1) break;
            r0 = n0; r1 = n1; r2 = n2; r3 = n3;
            cv1 = cv2; m1 = m2; j1 = j2;
        }
    }

    // merge the 4 sub-groups, then widen
    #pragma unroll
    for (int i = 0; i < 4; i++) {
        acc2[i] = __hadd2(acc2[i], shfl_xor_h2(acc2[i], 16));
        acc2[i] = __hadd2(acc2[i], shfl_xor_h2(acc2[i], 32));
    }
    float acc[8];
    #pragma unroll
    for (int i = 0; i < 4; i++) {
        float2 t = __half22float2(acc2[i]);
        acc[2 * i] = t.x; acc[2 * i + 1] = t.y;
    }

    float4 ba = *(const float4*)(b1 + f0);
    float4 bb = *(const float4*)(b1 + f0 + 4);
    float h[8];
    h[0] = fmaxf(fmaf(d, acc[0], ba.x), 0.0f);
    h[1] = fmaxf(fmaf(d, acc[1], ba.y), 0.0f);
    h[2] = fmaxf(fmaf(d, acc[2], ba.z), 0.0f);
    h[3] = fmaxf(fmaf(d, acc[3], ba.w), 0.0f);
    h[4] = fmaxf(fmaf(d, acc[4], bb.x), 0.0f);
    h[5] = fmaxf(fmaf(d, acc[5], bb.y), 0.0f);
    h[6] = fmaxf(fmaf(d, acc[6], bb.z), 0.0f);
    h[7] = fmaxf(fmaf(d, acc[7], bb.w), 0.0f);

    const int cb = (g == 0) ? 0 : (g == 1) ? 3 : (g == 2) ? 6 : 8;
    const int nc = (g < 2) ? 3 : 2;
    float p[3];
    #pragma unroll
    for (int ci = 0; ci < 3; ci++) {
        if (ci < nc) {
            int c = cb + ci;
            float4 wa = *(const float4*)(W2T + c * IN_F + f0);
            float4 wb = *(const float4*)(W2T + c * IN_F + f0 + 4);
            float t = fmaf(h[0], wa.x, fmaf(h[1], wa.y, fmaf(h[2], wa.z, h[3] * wa.w)));
            t = fmaf(h[4], wb.x, fmaf(h[5], wb.y, fmaf(h[6], wb.z, fmaf(h[7], wb.w, t))));
            #pragma unroll
            for (int off = 1; off < 16; off <<= 1) t += __shfl_xor(t, off, 64);
            p[ci] = t;
        }
    }
    if (l16 == 0) {
        __half* o = h2h + (size_t)node * H2P + cb;
        for (int ci = 0; ci < nc; ci++) o[ci] = __float2half(d * p[ci]);
    }
}

// ------- agg2: 2-deep pipelined maskless gather (32B rows) + softmax ---------
__global__ __launch_bounds__(256) void k_agg2(const __half* __restrict__ h2h,
                                              const int2* __restrict__ rowinfo,
                                              const int* __restrict__ csr,
                                              const float* __restrict__ dis,
                                              const float* __restrict__ b2,
                                              float* __restrict__ out,
                                              int N) {
    int t = blockIdx.x * 256 + threadIdx.x;
    int node = t >> 3;
    if (node >= N) return;
    int o = t & 7;
    int q = o & 1;          // which 8-half chunk of the 16-half row
    int eg = o >> 1;        // edge group 0..3
    const int base = q * 8;
    const __half2 hz = __half2half2(__float2half(0.0f));

    __half2 a2[4] = {hz, hz, hz, hz};
    if (eg == 0) {          // self term
        float4 r = *(const float4*)(h2h + (size_t)node * H2P + base);
        const __half2* hh = (const __half2*)&r;
        a2[0] = hh[0]; a2[1] = hh[1]; a2[2] = hh[2]; a2[3] = hh[3];
    }
    const int2 ri = rowinfo[node];
    const int end = ri.x + ri.y;

    int j0 = ri.x + 4 * eg;
    if (j0 < end) {
        int4a cv0 = *(const int4a*)(csr + j0);
        int  j1 = j0 + 16;
        bool m1 = j1 < end;
        int4a cv1 = m1 ? *(const int4a*)(csr + j1) : cv0;
        float4 r0 = *(const float4*)(h2h + (size_t)cv0[0] * H2P + base);
        float4 r1 = *(const float4*)(h2h + (size_t)cv0[1] * H2P + base);
        float4 r2 = *(const float4*)(h2h + (size_t)cv0[2] * H2P + base);
        float4 r3 = *(const float4*)(h2h + (size_t)cv0[3] * H2P + base);
        while (true) {
            const int  j2 = j1 + 16;
            const bool m2 = m1 && (j2 < end);
            int4a cv2 = m2 ? *(const int4a*)(csr + j2) : cv1;
            float4 n0, n1, n2, n3;
            if (m1) {
                n0 = *(const float4*)(h2h + (size_t)cv1[0] * H2P + base);
                n1 = *(const float4*)(h2h + (size_t)cv1[1] * H2P + base);
                n2 = *(const float4*)(h2h + (size_t)cv1[2] * H2P + base);
                n3 = *(const float4*)(h2h + (size_t)cv1[3] * H2P + base);
            }
            const __half2* h0 = (const __half2*)&r0;
            const __half2* h1 = (const __half2*)&r1;
            const __half2* h2 = (const __half2*)&r2;
            const __half2* h3 = (const __half2*)&r3;
            #pragma unroll
            for (int i = 0; i < 4; i++) {
                a2[i] = __hadd2(a2[i], h0[i]);
                a2[i] = __hadd2(a2[i], h1[i]);
                a2[i] = __hadd2(a2[i], h2[i]);
                a2[i] = __hadd2(a2[i], h3[i]);
            }
            if (!m1) break;
            r0 = n0; r1 = n1; r2 = n2; r3 = n3;
            cv1 = cv2; m1 = m2; j1 = j2;
        }
    }

    // merge the 4 edge-groups (masks 2 and 4 stay inside the 8-lane octet)
    #pragma unroll
    for (int i = 0; i < 4; i++) {
        a2[i] = __hadd2(a2[i], shfl_xor_h2(a2[i], 2));
        a2[i] = __hadd2(a2[i], shfl_xor_h2(a2[i], 4));
    }

    float a[8];
    #pragma unroll
    for (int i = 0; i < 4; i++) {
        float2 tt = __half22float2(a2[i]);
        a[2 * i] = tt.x; a[2 * i + 1] = tt.y;
    }

    const float d = dis[node];
    float vv[8];
    #pragma unroll
    for (int i = 0; i < 8; i++) {
        int f = base + i;
        vv[i] = (f < NC) ? fmaf(d, a[i], b2[f]) : -1e30f;
    }
    float m = vv[0];
    #pragma unroll
    for (int i = 1; i < 8; i++) m = fmaxf(m, vv[i]);
    m = fmaxf(m, __shfl_xor(m, 1, 64));
    float e[8];
    float s = 0.0f;
    #pragma unroll
    for (int i = 0; i < 8; i++) { e[i] = (base + i < NC) ? expf(vv[i] - m) : 0.0f; s += e[i]; }
    s += __shfl_xor(s, 1, 64);
    float inv = 1.0f / s;

    float* op = out + (size_t)node * NC;
    if (o == 0) {
        *(float2*)(op + 0) = make_float2(e[0] * inv, e[1] * inv);
        *(float2*)(op + 2) = make_float2(e[2] * inv, e[3] * inv);
        *(float2*)(op + 4) = make_float2(e[4] * inv, e[5] * inv);
        *(float2*)(op + 6) = make_float2(e[6] * inv, e[7] * inv);
    } else if (o == 1) {
        *(float2*)(op + 8) = make_float2(e[0] * inv, e[1] * inv);
    }
}

extern "C" void kernel_launch(void* const* d_in, const int* in_sizes, int n_in,
                              void* d_out, int out_size, void* d_ws, size_t ws_size,
                              hipStream_t stream) {
    const float* x  = (const float*)d_in[0];
    const int*   ei = (const int*)d_in[1];
    const float* W1 = (const float*)d_in[2];
    const float* b1 = (const float*)d_in[3];
    const float* W2 = (const float*)d_in[4];
    const float* b2 = (const float*)d_in[5];
    float* out = (float*)d_out;

    const int N = in_sizes[0] / IN_F;   // 100000
    const int E = in_sizes[1] / 2;      // 1600000
    const int* esrc = ei;
    const int* edst = ei + E;
    const int nbin = (N + NPB - 1) / NPB;  // 782

    char* ws = (char*)d_ws;
    int2*   rowinfo = (int2*)(ws);                          // N*8   = 800 KB
    float*  dis     = (float*)(ws + 0x100000);              // 400 KB
    int*    bcnt    = (int*)(ws + 0x180000);                // 3.1 KB
    __half* WT      = (__half*)(ws + 0x190000);             // 32 KB
    float*  W2T     = (float*)(ws + 0x1A0000);              // 5 KB
    unsigned int* binned = (unsigned int*)(ws + 0x200000);  // 8.0 MB
    int*    csr     = (int*)(ws + 0xA00000);                // 9.2 MB (padded, bin-strided)
    __half* hsh     = (__half*)(ws + 0x1400000);            // 25.6 MB (+ sentinel row N)
    __half* h2h     = (__half*)(ws + 0x2D00000);            // 3.2 MB (+ sentinel row N)

    hipMemsetAsync(bcnt, 0, (size_t)nbin * sizeof(int), stream);

    k_bin <<<(E + EPB - 1) / EPB, 1024, 0, stream>>>(esrc, edst, bcnt, binned, W1, WT, W2, W2T, E, nbin);
    k_pg  <<<nbin, 512, 0, stream>>>(bcnt, binned, rowinfo, dis, csr, x, WT, hsh, h2h, N);
    k_agg1<<<(N + 3) / 4, 256, 0, stream>>>(hsh, rowinfo, csr, dis, b1, W2T, h2h, N);
    k_agg2<<<(int)(((size_t)N * 8 + 255) / 256), 256, 0, stream>>>(h2h, rowinfo, csr, dis, b2, out, N);
}

// Round 9
// 221.628 us; speedup vs baseline: 1.0479x; 1.0131x over previous
//
#include <hip/hip_runtime.h>
#include <hip/hip_fp16.h>

#define IN_F 128
#define HID  128
#define NC   10
#define H2P  16     // h2 row stride in HALVES (32 B)
#define NPB  128    // nodes per bin (bin = dst>>7, local = dst&127)
#define NBMAX 784   // max bins (N=100000 -> 782)
#define BCAP 2560   // per-bin edge capacity (mean 2046, +11 sigma)
#define CAPP 2944   // per-bin PADDED csr capacity: BCAP + NPB*3 (each node padded to x4)
#define EPB  4096   // edges per k_bin block (1024 thr x 4)
#define LDW  136    // padded LDS row stride in halves (272B -> lane-bank stride 4, ~2-way)

typedef _Float16 f16x8 __attribute__((ext_vector_type(8)));
typedef float f32x4 __attribute__((ext_vector_type(4)));
typedef int int4a __attribute__((ext_vector_type(4), aligned(4)));  // 4B-aligned vec4

__device__ inline __half2 shfl_xor_h2(__half2 v, int mask) {
    int i = __shfl_xor(*reinterpret_cast<int*>(&v), mask, 64);
    return *reinterpret_cast<__half2*>(&i);
}

// ------- phase A: bin edges by dst>>7, packed (dl<<17)|src; blk0 preps WT/W2T.
// int4 edge loads; wave-shfl scan (3 barriers, was 20); LDS-staged bin-sorted
// writeout so binned[] writes are coalesced runs.
__global__ __launch_bounds__(1024) void k_bin(const int* __restrict__ src,
                                              const int* __restrict__ dst,
                                              int* __restrict__ bcnt,
                                              unsigned int* __restrict__ binned,
                                              const float* __restrict__ W1,
                                              __half* __restrict__ WT,
                                              const float* __restrict__ W2,
                                              float* __restrict__ W2T,
                                              int E, int nbin) {
    __shared__ int hist[NBMAX];
    __shared__ int base[NBMAX];
    __shared__ int lofs[NBMAX];
    __shared__ int lcur[NBMAX];
    __shared__ int wsum[16];
    __shared__ unsigned int stage[EPB];
    __shared__ unsigned short sbin[EPB];
    const int tid = threadIdx.x;

    if (blockIdx.x == 0) {   // WT[n][k] = fp16(W1[k][n]); W2T[c][f] = W2[f][c]
        for (int i = tid; i < IN_F * HID; i += 1024) {
            int k = i >> 7, n = i & 127;
            WT[n * IN_F + k] = __float2half(W1[k * HID + n]);
        }
        for (int i = tid; i < NC * IN_F; i += 1024)
            W2T[i] = W2[(i & 127) * NC + (i >> 7)];
    }

    for (int b = tid; b < nbin; b += 1024) { hist[b] = 0; lcur[b] = 0; }
    __syncthreads();

    // 4 consecutive edges per thread, vectorized
    const int e0 = blockIdx.x * EPB + tid * 4;
    int d[4], s[4];
    if (e0 + 3 < E) {
        int4a dv = *(const int4a*)(dst + e0);
        int4a sv = *(const int4a*)(src + e0);
        d[0] = dv[0]; d[1] = dv[1]; d[2] = dv[2]; d[3] = dv[3];
        s[0] = sv[0]; s[1] = sv[1]; s[2] = sv[2]; s[3] = sv[3];
    } else {
        #pragma unroll
        for (int u = 0; u < 4; u++) {
            d[u] = (e0 + u < E) ? dst[e0 + u] : -1;
            s[u] = (e0 + u < E) ? src[e0 + u] : 0;
        }
    }
    #pragma unroll
    for (int u = 0; u < 4; u++)
        if (d[u] >= 0) atomicAdd(&hist[d[u] >> 7], 1);
    __syncthreads();

    // global reservation per bin
    for (int b = tid; b < nbin; b += 1024) {
        int h = hist[b];
        base[b] = h ? atomicAdd(&bcnt[b], h) : 0;
    }
    // wave-level exclusive scan of hist over 1024 slots (16 waves x 64)
    int v = (tid < nbin) ? hist[tid] : 0;
    int inc = v;
    #pragma unroll
    for (int off = 1; off < 64; off <<= 1) {
        int t = __shfl_up(inc, off, 64);
        if ((tid & 63) >= off) inc += t;
    }
    if ((tid & 63) == 63) wsum[tid >> 6] = inc;
    __syncthreads();
    if (tid < 64) {        // exclusive scan of the 16 wave totals (wave 0)
        int wv = (tid < 16) ? wsum[tid] : 0;
        int winc = wv;
        #pragma unroll
        for (int off = 1; off < 16; off <<= 1) {
            int t = __shfl_up(winc, off, 64);
            if (tid >= off) winc += t;
        }
        if (tid < 16) wsum[tid] = winc - wv;
    }
    __syncthreads();
    if (tid < nbin) lofs[tid] = inc - v + wsum[tid >> 6];
    __syncthreads();

    // scatter into LDS stage (sorted by bin)
    #pragma unroll
    for (int u = 0; u < 4; u++) {
        if (d[u] >= 0) {
            int b = d[u] >> 7;
            int slot = lofs[b] + atomicAdd(&lcur[b], 1);
            stage[slot] = ((unsigned)(d[u] & 127) << 17) | (unsigned)s[u];
            sbin[slot] = (unsigned short)b;
        }
    }
    __syncthreads();
    // coalesced streamout
    const int total = lofs[nbin - 1] + hist[nbin - 1];
    for (int i = tid; i < total; i += 1024) {
        int b = sbin[i];
        int o = base[b] + (i - lofs[b]);
        if (o < BCAP) binned[(size_t)b * BCAP + o] = stage[i];
    }
}

// ------- phase B (fused): place (hist/wave-scan/scatter, padded bin-strided
// CSR) then MFMA GEMM1. 1024 threads, single GEMM pass over 4 tiles; binned
// read ONCE into 3 static registers (hist + scatter); ~7 barriers total.
__global__ __launch_bounds__(1024) void k_pg(const int* __restrict__ bcnt,
                                             const unsigned int* __restrict__ binned,
                                             int2* __restrict__ rowinfo,
                                             float* __restrict__ dis,
                                             int* __restrict__ csr,
                                             const float* __restrict__ X,
                                             const __half* __restrict__ WT,
                                             __half* __restrict__ hsh,
                                             __half* __restrict__ h2h,
                                             int N) {
    __shared__ int h[NPB];
    __shared__ int lb[NPB];
    __shared__ int cur[NPB];
    __shared__ float sdis[NPB];
    __shared__ int wtot[2];
    __shared__ _Float16 sX[4][32 * LDW];
    __shared__ _Float16 sW[128 * LDW];
    const int b = blockIdx.x;
    const int tid = threadIdx.x;

    if (tid < NPB) h[tid] = 0;
    __syncthreads();

    const int m = min(bcnt[b], BCAP);
    const unsigned int* p = binned + (size_t)b * BCAP;
    // binned read once: <=3 entries/thread (BCAP=2560, stride 1024), static regs
    const int i0 = tid, i1 = tid + 1024, i2 = tid + 2048;
    unsigned pv0 = 0, pv1 = 0, pv2 = 0;
    if (i0 < m) { pv0 = p[i0]; atomicAdd(&h[pv0 >> 17], 1); }
    if (i1 < m) { pv1 = p[i1]; atomicAdd(&h[pv1 >> 17], 1); }
    if (i2 < m) { pv2 = p[i2]; atomicAdd(&h[pv2 >> 17], 1); }
    __syncthreads();

    int myh = 0, cnt4 = 0;
    if (tid < NPB) { myh = h[tid]; cnt4 = (myh + 3) & ~3; }
    // inclusive wave scan of cnt4 over waves 0,1
    int inc = cnt4;
    if (tid < NPB) {
        #pragma unroll
        for (int off = 1; off < 64; off <<= 1) {
            int t = __shfl_up(inc, off, 64);
            if ((tid & 63) >= off) inc += t;
        }
        if ((tid & 63) == 63) wtot[tid >> 6] = inc;
    }
    __syncthreads();
    int ex = 0;
    if (tid < NPB) {
        ex = inc - cnt4 + ((tid >= 64) ? wtot[0] : 0);
        int node = b * NPB + tid;
        if (node < N) {
            rowinfo[node] = make_int2(b * CAPP + ex, cnt4);
            float dd = rsqrtf(1.0f + (float)myh);
            dis[node] = dd;
            sdis[tid] = dd;
        }
        lb[tid] = ex;     // exclusive offsets for scatter
        cur[tid] = 0;
    }
    __syncthreads();
    if (i0 < m) { int dl = pv0 >> 17; int r = atomicAdd(&cur[dl], 1); csr[b * CAPP + lb[dl] + r] = (int)(pv0 & 0x1FFFF); }
    if (i1 < m) { int dl = pv1 >> 17; int r = atomicAdd(&cur[dl], 1); csr[b * CAPP + lb[dl] + r] = (int)(pv1 & 0x1FFFF); }
    if (i2 < m) { int dl = pv2 >> 17; int r = atomicAdd(&cur[dl], 1); csr[b * CAPP + lb[dl] + r] = (int)(pv2 & 0x1FFFF); }
    if (tid < NPB) {        // pad tail of each node's list with sentinel N
        for (int k = myh; k < cnt4; k++) csr[b * CAPP + ex + k] = N;
    }
    if (b == 0) {           // zero rows for the sentinel node
        f16x8 z = {0, 0, 0, 0, 0, 0, 0, 0};
        if (tid < 16) *(f16x8*)(hsh + (size_t)N * HID + tid * 8) = z;
        if (tid < 2)  *(f16x8*)(h2h + (size_t)N * H2P + tid * 8) = z;
    }

    // stage WT -> sW (1024 threads: 8 threads/row, 2 x 16B chunks each)
    {
        int n = tid >> 3, c = tid & 7;
        const f16x8* srcp = (const f16x8*)(WT + n * IN_F);
        f16x8* dstp = (f16x8*)(sW + n * LDW);
        dstp[c]     = srcp[c];
        dstp[c + 8] = srcp[c + 8];
    }
    {   // stage all 4 X tiles (fp32 -> fp16), rows clamped at N-1
        const int sub = tid >> 8;         // tile 0..3
        const int t256 = tid & 255;
        const int r = t256 >> 3;
        const int k0 = (t256 & 7) * 16;
        int row = b * NPB + sub * 32 + r;
        if (row >= N) row = N - 1;
        const float* sp = X + (size_t)row * IN_F + k0;
        float4 f0 = *(const float4*)(sp);
        float4 f1 = *(const float4*)(sp + 4);
        float4 f2 = *(const float4*)(sp + 8);
        float4 f3 = *(const float4*)(sp + 12);
        f16x8 h0, h1;
        h0[0] = (_Float16)f0.x; h0[1] = (_Float16)f0.y;
        h0[2] = (_Float16)f0.z; h0[3] = (_Float16)f0.w;
        h0[4] = (_Float16)f1.x; h0[5] = (_Float16)f1.y;
        h0[6] = (_Float16)f1.z; h0[7] = (_Float16)f1.w;
        h1[0] = (_Float16)f2.x; h1[1] = (_Float16)f2.y;
        h1[2] = (_Float16)f2.z; h1[3] = (_Float16)f2.w;
        h1[4] = (_Float16)f3.x; h1[5] = (_Float16)f3.y;
        h1[6] = (_Float16)f3.z; h1[7] = (_Float16)f3.w;
        *(f16x8*)(sX[sub] + r * LDW + k0) = h0;
        *(f16x8*)(sX[sub] + r * LDW + k0 + 8) = h1;
    }
    __syncthreads();

    // GEMM: 16 waves; wave w computes tile (w>>2), N-columns ((w&3)*32..+32)
    const int wave = tid >> 6;
    const int grp  = wave >> 2;       // tile 0..3
    const int nbase = (wave & 3) * 32;
    const int lane = tid & 63;
    const int quad = lane >> 4;
    const int l16 = lane & 15;

    f32x4 acc00 = {0,0,0,0}, acc01 = {0,0,0,0}, acc10 = {0,0,0,0}, acc11 = {0,0,0,0};
    #pragma unroll
    for (int kc = 0; kc < 4; kc++) {
        const int koff = kc * 32 + quad * 8;
        f16x8 a0 = *(const f16x8*)(sX[grp] + l16 * LDW + koff);
        f16x8 a1 = *(const f16x8*)(sX[grp] + (16 + l16) * LDW + koff);
        f16x8 b0 = *(const f16x8*)(sW + (nbase + l16) * LDW + koff);
        f16x8 b1 = *(const f16x8*)(sW + (nbase + 16 + l16) * LDW + koff);
        acc00 = __builtin_amdgcn_mfma_f32_16x16x32_f16(a0, b0, acc00, 0, 0, 0);
        acc01 = __builtin_amdgcn_mfma_f32_16x16x32_f16(a0, b1, acc01, 0, 0, 0);
        acc10 = __builtin_amdgcn_mfma_f32_16x16x32_f16(a1, b0, acc10, 0, 0, 0);
        acc11 = __builtin_amdgcn_mfma_f32_16x16x32_f16(a1, b1, acc11, 0, 0, 0);
    }
    #pragma unroll
    for (int r = 0; r < 4; r++) {
        {
            int lr = grp * 32 + quad * 4 + r;
            int row = b * NPB + lr;
            if (row < N) {
                float d = sdis[lr];
                __half* o = hsh + (size_t)row * HID + nbase + l16;
                o[0]  = __float2half(acc00[r] * d);
                o[16] = __float2half(acc01[r] * d);
            }
        }
        {
            int lr = grp * 32 + 16 + quad * 4 + r;
            int row = b * NPB + lr;
            if (row < N) {
                float d = sdis[lr];
                __half* o = hsh + (size_t)row * HID + nbase + l16;
                o[0]  = __float2half(acc10[r] * d);
                o[16] = __float2half(acc11[r] * d);
            }
        }
    }
}

// ------- agg1: 2-deep pipelined maskless gather + bias/ReLU + GEMM2 ----------
__global__ __launch_bounds__(256) void k_agg1(const __half* __restrict__ hsh,
                                              const int2* __restrict__ rowinfo,
                                              const int* __restrict__ csr,
                                              const float* __restrict__ dis,
                                              const float* __restrict__ b1,
                                              const float* __restrict__ W2T,
                                              __half* __restrict__ h2h,
                                              int N) {
    const int node = blockIdx.x * 4 + (threadIdx.x >> 6);
    if (node >= N) return;
    const int lane = threadIdx.x & 63;
    const int g   = lane >> 4;
    const int l16 = lane & 15;
    const int f0  = l16 * 8;       // 8 halves per lane
    const __half2 hz = __half2half2(__float2half(0.0f));

    const int2 ri = rowinfo[node];
    const int beg = ri.x, end = ri.x + ri.y;
    const float d = dis[node];

    __half2 acc2[4] = {hz, hz, hz, hz};
    if (g == 0) {   // self term (hsh pre-scaled by dis[src])
        float4 r = *(const float4*)(hsh + (size_t)node * HID + f0);
        const __half2* hh = (const __half2*)&r;
        acc2[0] = hh[0]; acc2[1] = hh[1]; acc2[2] = hh[2]; acc2[3] = hh[3];
    }

    int j0 = beg + 4 * g;
    if (j0 < end) {
        int4a cv0 = *(const int4a*)(csr + j0);
        int  j1 = j0 + 16;
        bool m1 = j1 < end;
        int4a cv1 = m1 ? *(const int4a*)(csr + j1) : cv0;
        float4 r0 = *(const float4*)(hsh + (size_t)cv0[0] * HID + f0);
        float4 r1 = *(const float4*)(hsh + (size_t)cv0[1] * HID + f0);
        float4 r2 = *(const float4*)(hsh + (size_t)cv0[2] * HID + f0);
        float4 r3 = *(const float4*)(hsh + (size_t)cv0[3] * HID + f0);
        while (true) {
            const int  j2 = j1 + 16;
            const bool m2 = m1 && (j2 < end);
            int4a cv2 = m2 ? *(const int4a*)(csr + j2) : cv1;
            float4 n0, n1, n2, n3;
            if (m1) {
                n0 = *(const float4*)(hsh + (size_t)cv1[0] * HID + f0);
                n1 = *(const float4*)(hsh + (size_t)cv1[1] * HID + f0);
                n2 = *(const float4*)(hsh + (size_t)cv1[2] * HID + f0);
                n3 = *(const float4*)(hsh + (size_t)cv1[3] * HID + f0);
            }
            const __half2* h0 = (const __half2*)&r0;
            const __half2* h1 = (const __half2*)&r1;
            const __half2* h2 = (const __half2*)&r2;
            const __half2* h3 = (const __half2*)&r3;
            #pragma unroll
            for (int i = 0; i < 4; i++) {
                acc2[i] = __hadd2(acc2[i], h0[i]);
                acc2[i] = __hadd2(acc2[i], h1[i]);
                acc2[i] = __hadd2(acc2[i], h2[i]);
                acc2[i] = __hadd2(acc2[i], h3[i]);
            }
            if (!m1) break;
            r0 = n0; r1 = n1; r2 = n2; r3 = n3;
            cv1 = cv2; m1 = m2; j1 = j2;
        }
    }

    // merge the 4 sub-groups, then widen
    #pragma unroll
    for (int i = 0; i < 4; i++) {
        acc2[i] = __hadd2(acc2[i], shfl_xor_h2(acc2[i], 16));
        acc2[i] = __hadd2(acc2[i], shfl_xor_h2(acc2[i], 32));
    }
    float acc[8];
    #pragma unroll
    for (int i = 0; i < 4; i++) {
        float2 t = __half22float2(acc2[i]);
        acc[2 * i] = t.x; acc[2 * i + 1] = t.y;
    }

    float4 ba = *(const float4*)(b1 + f0);
    float4 bb = *(const float4*)(b1 + f0 + 4);
    float h[8];
    h[0] = fmaxf(fmaf(d, acc[0], ba.x), 0.0f);
    h[1] = fmaxf(fmaf(d, acc[1], ba.y), 0.0f);
    h[2] = fmaxf(fmaf(d, acc[2], ba.z), 0.0f);
    h[3] = fmaxf(fmaf(d, acc[3], ba.w), 0.0f);
    h[4] = fmaxf(fmaf(d, acc[4], bb.x), 0.0f);
    h[5] = fmaxf(fmaf(d, acc[5], bb.y), 0.0f);
    h[6] = fmaxf(fmaf(d, acc[6], bb.z), 0.0f);
    h[7] = fmaxf(fmaf(d, acc[7], bb.w), 0.0f);

    const int cb = (g == 0) ? 0 : (g == 1) ? 3 : (g == 2) ? 6 : 8;
    const int nc = (g < 2) ? 3 : 2;
    float p[3];
    #pragma unroll
    for (int ci = 0; ci < 3; ci++) {
        if (ci < nc) {
            int c = cb + ci;
            float4 wa = *(const float4*)(W2T + c * IN_F + f0);
            float4 wb = *(const float4*)(W2T + c * IN_F + f0 + 4);
            float t = fmaf(h[0], wa.x, fmaf(h[1], wa.y, fmaf(h[2], wa.z, h[3] * wa.w)));
            t = fmaf(h[4], wb.x, fmaf(h[5], wb.y, fmaf(h[6], wb.z, fmaf(h[7], wb.w, t))));
            #pragma unroll
            for (int off = 1; off < 16; off <<= 1) t += __shfl_xor(t, off, 64);
            p[ci] = t;
        }
    }
    if (l16 == 0) {
        __half* o = h2h + (size_t)node * H2P + cb;
        for (int ci = 0; ci < nc; ci++) o[ci] = __float2half(d * p[ci]);
    }
}

// ------- agg2: 2-deep pipelined maskless gather (32B rows) + softmax ---------
__global__ __launch_bounds__(256) void k_agg2(const __half* __restrict__ h2h,
                                              const int2* __restrict__ rowinfo,
                                              const int* __restrict__ csr,
                                              const float* __restrict__ dis,
                                              const float* __restrict__ b2,
                                              float* __restrict__ out,
                                              int N) {
    int t = blockIdx.x * 256 + threadIdx.x;
    int node = t >> 3;
    if (node >= N) return;
    int o = t & 7;
    int q = o & 1;          // which 8-half chunk of the 16-half row
    int eg = o >> 1;        // edge group 0..3
    const int base = q * 8;
    const __half2 hz = __half2half2(__float2half(0.0f));

    __half2 a2[4] = {hz, hz, hz, hz};
    if (eg == 0) {          // self term
        float4 r = *(const float4*)(h2h + (size_t)node * H2P + base);
        const __half2* hh = (const __half2*)&r;
        a2[0] = hh[0]; a2[1] = hh[1]; a2[2] = hh[2]; a2[3] = hh[3];
    }
    const int2 ri = rowinfo[node];
    const int end = ri.x + ri.y;

    int j0 = ri.x + 4 * eg;
    if (j0 < end) {
        int4a cv0 = *(const int4a*)(csr + j0);
        int  j1 = j0 + 16;
        bool m1 = j1 < end;
        int4a cv1 = m1 ? *(const int4a*)(csr + j1) : cv0;
        float4 r0 = *(const float4*)(h2h + (size_t)cv0[0] * H2P + base);
        float4 r1 = *(const float4*)(h2h + (size_t)cv0[1] * H2P + base);
        float4 r2 = *(const float4*)(h2h + (size_t)cv0[2] * H2P + base);
        float4 r3 = *(const float4*)(h2h + (size_t)cv0[3] * H2P + base);
        while (true) {
            const int  j2 = j1 + 16;
            const bool m2 = m1 && (j2 < end);
            int4a cv2 = m2 ? *(const int4a*)(csr + j2) : cv1;
            float4 n0, n1, n2, n3;
            if (m1) {
                n0 = *(const float4*)(h2h + (size_t)cv1[0] * H2P + base);
                n1 = *(const float4*)(h2h + (size_t)cv1[1] * H2P + base);
                n2 = *(const float4*)(h2h + (size_t)cv1[2] * H2P + base);
                n3 = *(const float4*)(h2h + (size_t)cv1[3] * H2P + base);
            }
            const __half2* h0 = (const __half2*)&r0;
            const __half2* h1 = (const __half2*)&r1;
            const __half2* h2 = (const __half2*)&r2;
            const __half2* h3 = (const __half2*)&r3;
            #pragma unroll
            for (int i = 0; i < 4; i++) {
                a2[i] = __hadd2(a2[i], h0[i]);
                a2[i] = __hadd2(a2[i], h1[i]);
                a2[i] = __hadd2(a2[i], h2[i]);
                a2[i] = __hadd2(a2[i], h3[i]);
            }
            if (!m1) break;
            r0 = n0; r1 = n1; r2 = n2; r3 = n3;
            cv1 = cv2; m1 = m2; j1 = j2;
        }
    }

    // merge the 4 edge-groups (masks 2 and 4 stay inside the 8-lane octet)
    #pragma unroll
    for (int i = 0; i < 4; i++) {
        a2[i] = __hadd2(a2[i], shfl_xor_h2(a2[i], 2));
        a2[i] = __hadd2(a2[i], shfl_xor_h2(a2[i], 4));
    }

    float a[8];
    #pragma unroll
    for (int i = 0; i < 4; i++) {
        float2 tt = __half22float2(a2[i]);
        a[2 * i] = tt.x; a[2 * i + 1] = tt.y;
    }

    const float d = dis[node];
    float vv[8];
    #pragma unroll
    for (int i = 0; i < 8; i++) {
        int f = base + i;
        vv[i] = (f < NC) ? fmaf(d, a[i], b2[f]) : -1e30f;
    }
    float m = vv[0];
    #pragma unroll
    for (int i = 1; i < 8; i++) m = fmaxf(m, vv[i]);
    m = fmaxf(m, __shfl_xor(m, 1, 64));
    float e[8];
    float s = 0.0f;
    #pragma unroll
    for (int i = 0; i < 8; i++) { e[i] = (base + i < NC) ? expf(vv[i] - m) : 0.0f; s += e[i]; }
    s += __shfl_xor(s, 1, 64);
    float inv = 1.0f / s;

    float* op = out + (size_t)node * NC;
    if (o == 0) {
        *(float2*)(op + 0) = make_float2(e[0] * inv, e[1] * inv);
        *(float2*)(op + 2) = make_float2(e[2] * inv, e[3] * inv);
        *(float2*)(op + 4) = make_float2(e[4] * inv, e[5] * inv);
        *(float2*)(op + 6) = make_float2(e[6] * inv, e[7] * inv);
    } else if (o == 1) {
        *(float2*)(op + 8) = make_float2(e[0] * inv, e[1] * inv);
    }
}

extern "C" void kernel_launch(void* const* d_in, const int* in_sizes, int n_in,
                              void* d_out, int out_size, void* d_ws, size_t ws_size,
                              hipStream_t stream) {
    const float* x  = (const float*)d_in[0];
    const int*   ei = (const int*)d_in[1];
    const float* W1 = (const float*)d_in[2];
    const float* b1 = (const float*)d_in[3];
    const float* W2 = (const float*)d_in[4];
    const float* b2 = (const float*)d_in[5];
    float* out = (float*)d_out;

    const int N = in_sizes[0] / IN_F;   // 100000
    const int E = in_sizes[1] / 2;      // 1600000
    const int* esrc = ei;
    const int* edst = ei + E;
    const int nbin = (N + NPB - 1) / NPB;  // 782

    char* ws = (char*)d_ws;
    int2*   rowinfo = (int2*)(ws);                          // N*8   = 800 KB
    float*  dis     = (float*)(ws + 0x100000);              // 400 KB
    int*    bcnt    = (int*)(ws + 0x180000);                // 3.1 KB
    __half* WT      = (__half*)(ws + 0x190000);             // 32 KB
    float*  W2T     = (float*)(ws + 0x1A0000);              // 5 KB
    unsigned int* binned = (unsigned int*)(ws + 0x200000);  // 8.0 MB
    int*    csr     = (int*)(ws + 0xA00000);                // 9.2 MB (padded, bin-strided)
    __half* hsh     = (__half*)(ws + 0x1400000);            // 25.6 MB (+ sentinel row N)
    __half* h2h     = (__half*)(ws + 0x2D00000);            // 3.2 MB (+ sentinel row N)

    hipMemsetAsync(bcnt, 0, (size_t)nbin * sizeof(int), stream);

    k_bin <<<(E + EPB - 1) / EPB, 1024, 0, stream>>>(esrc, edst, bcnt, binned, W1, WT, W2, W2T, E, nbin);
    k_pg  <<<nbin, 1024, 0, stream>>>(bcnt, binned, rowinfo, dis, csr, x, WT, hsh, h2h, N);
    k_agg1<<<(N + 3) / 4, 256, 0, stream>>>(hsh, rowinfo, csr, dis, b1, W2T, h2h, N);
    k_agg2<<<(int)(((size_t)N * 8 + 255) / 256), 256, 0, stream>>>(h2h, rowinfo, csr, dis, b2, out, N);
}